// Round 1
// baseline (311.037 us; speedup 1.0000x reference)
//
#include <hip/hip_runtime.h>

// Problem constants (from reference setup_inputs)
#define BB 32
#define LL 4
#define SS 512
#define DD 768
#define D4 (DD / 4)   // 192 float4 lanes per row
#define GG 24         // NUM_SEGMENTS

// Binary search over a sorted row of length SS.
__device__ __forceinline__ int lower_bound_i(const int* __restrict__ a, int v) {
    int lo = 0, hi = SS;
    while (lo < hi) { int m = (lo + hi) >> 1; if (a[m] < v) lo = m + 1; else hi = m; }
    return lo;
}
__device__ __forceinline__ int upper_bound_i(const int* __restrict__ a, int v) {
    int lo = 0, hi = SS;
    while (lo < hi) { int m = (lo + hi) >> 1; if (a[m] <= v) lo = m + 1; else hi = m; }
    return lo;
}

// Kernel A: word_embeddings[b,g,:] = sum over tokens s with tgid[b,s]==g of sum_l emb[b,l,s,:]
// One block per (g, b). token_group_ids sorted per row -> contiguous token range.
// Every (b,g) slot written exactly once (zeros if no tokens) -> poison-safe, no atomics.
__global__ __launch_bounds__(D4) void word_agg_kernel(
    const float4* __restrict__ emb, const int* __restrict__ tg, float4* __restrict__ word)
{
    const int g = blockIdx.x;
    const int b = blockIdx.y;
    const int* row = tg + b * SS;
    const int lo = lower_bound_i(row, g);
    const int hi = upper_bound_i(row, g);
    const int d = threadIdx.x;

    float4 acc = make_float4(0.f, 0.f, 0.f, 0.f);
    for (int s = lo; s < hi; ++s) {
#pragma unroll
        for (int l = 0; l < LL; ++l) {
            float4 v = emb[((size_t)((b * LL + l) * SS + s)) * D4 + d];
            acc.x += v.x; acc.y += v.y; acc.z += v.z; acc.w += v.w;
        }
    }
    word[((size_t)(b * SS + g)) * D4 + d] = acc;
}

// Kernel B: seg_embeddings[b,t,:] = sum over word slots g with segid[b,g]==t of word[b,g,:]
// segment_ids sorted per row -> contiguous range. One block per (t, b).
__global__ __launch_bounds__(D4) void seg_agg_kernel(
    const float4* __restrict__ word, const int* __restrict__ sg, float4* __restrict__ seg)
{
    const int t = blockIdx.x;
    const int b = blockIdx.y;
    const int* row = sg + b * SS;
    const int lo = lower_bound_i(row, t);
    const int hi = upper_bound_i(row, t);
    const int d = threadIdx.x;

    float4 acc = make_float4(0.f, 0.f, 0.f, 0.f);
    for (int g = lo; g < hi; ++g) {
        float4 v = word[((size_t)(b * SS + g)) * D4 + d];
        acc.x += v.x; acc.y += v.y; acc.z += v.z; acc.w += v.w;
    }
    seg[((size_t)(b * GG + t)) * D4 + d] = acc;
}

// Kernel C: sent_embeddings[b,:] = (1/512) * sum_t seg[b,t,:]   (algebraic identity:
// segment_sum over all 512 word slots partitions them across the 24 segments)
// plus seg_mask[b,j] = (j >= segid[b,511]+1) as 0/1 floats.
__global__ __launch_bounds__(D4) void sent_mask_kernel(
    const float4* __restrict__ seg, const int* __restrict__ sg,
    float4* __restrict__ sent, float* __restrict__ mask)
{
    const int b = blockIdx.x;
    const int d = threadIdx.x;

    float4 acc = make_float4(0.f, 0.f, 0.f, 0.f);
#pragma unroll
    for (int t = 0; t < GG; ++t) {
        float4 v = seg[((size_t)(b * GG + t)) * D4 + d];
        acc.x += v.x; acc.y += v.y; acc.z += v.z; acc.w += v.w;
    }
    const float inv = 1.0f / (float)SS;
    acc.x *= inv; acc.y *= inv; acc.z *= inv; acc.w *= inv;
    sent[(size_t)b * D4 + d] = acc;

    if (d < GG) {
        const int seg_num = sg[b * SS + (SS - 1)] + 1;  // sorted -> last elem is max
        mask[b * GG + d] = (d >= seg_num) ? 1.0f : 0.0f;
    }
}

extern "C" void kernel_launch(void* const* d_in, const int* in_sizes, int n_in,
                              void* d_out, int out_size, void* d_ws, size_t ws_size,
                              hipStream_t stream) {
    const float* emb = (const float*)d_in[0];           // [32,4,512,768] fp32
    const int*   tg  = (const int*)d_in[1];             // [32,512]
    const int*   sg  = (const int*)d_in[2];             // [32,512]

    float* out  = (float*)d_out;
    float* word = out;                                   // [32,512,768] -> 12,582,912
    float* sent = word + (size_t)BB * SS * DD;           // [32,768]     -> 24,576
    float* seg  = sent + (size_t)BB * DD;                // [32,24,768]  -> 589,824
    float* mask = seg  + (size_t)BB * GG * DD;           // [32,24]      -> 768

    word_agg_kernel<<<dim3(SS, BB), D4, 0, stream>>>((const float4*)emb, tg, (float4*)word);
    seg_agg_kernel<<<dim3(GG, BB), D4, 0, stream>>>((const float4*)word, sg, (float4*)seg);
    sent_mask_kernel<<<BB, D4, 0, stream>>>((const float4*)seg, sg, (float4*)sent, mask);
}

// Round 3
// 298.751 us; speedup vs baseline: 1.0411x; 1.0411x over previous
//
#include <hip/hip_runtime.h>

// Problem constants (from reference setup_inputs)
#define BB 32
#define LL 4
#define SS 512
#define DD 768
#define D4 (DD / 4)   // 192 float4 lanes per row
#define GG 24         // NUM_SEGMENTS

// Native clang vector type — required for __builtin_nontemporal_load
typedef float floatx4 __attribute__((ext_vector_type(4)));

// Workspace layout (ints): word_bounds[BB][SS+1], seg_bounds[BB][GG+1]
#define WB_STRIDE (SS + 1)
#define SB_STRIDE (GG + 1)

// ---------------------------------------------------------------------------
// Kernel P: precompute lower-bound boundaries for both id arrays, per batch.
// One block per b; ids cached in LDS so each 9-step binary search is LDS-only.
// wb[b][v] = lower_bound(tg_row, v) for v in 0..512  (word g owns [wb[g], wb[g+1]))
// sb[b][v] = lower_bound(sg_row, v) for v in 0..24   (seg  t owns [sb[t], sb[t+1]))
// ---------------------------------------------------------------------------
__global__ __launch_bounds__(SS) void bounds_kernel(
    const int* __restrict__ tg, const int* __restrict__ sg,
    int* __restrict__ wb, int* __restrict__ sb)
{
    __shared__ int ltg[SS];
    __shared__ int lsg[SS];
    const int b = blockIdx.x;
    const int t = threadIdx.x;
    ltg[t] = tg[b * SS + t];
    lsg[t] = sg[b * SS + t];
    __syncthreads();

    // lower_bound of value v=t in ltg
    {
        int v = t, lo = 0, hi = SS;
        while (lo < hi) { int m = (lo + hi) >> 1; if (ltg[m] < v) lo = m + 1; else hi = m; }
        wb[b * WB_STRIDE + t] = lo;
        if (t == 0) wb[b * WB_STRIDE + SS] = SS;
    }
    // lower_bound of value v=t in lsg, for t in 0..GG
    if (t <= GG) {
        int v = t, lo = 0, hi = SS;
        while (lo < hi) { int m = (lo + hi) >> 1; if (lsg[m] < v) lo = m + 1; else hi = m; }
        sb[b * SB_STRIDE + t] = lo;
    }
}

// ---------------------------------------------------------------------------
// Kernel A: word_embeddings[b,g,:] = sum_{s in [wb[g],wb[g+1])} sum_l emb[b,l,s,:]
// One block per (g,b); 192 threads = one float4 lane each. Bounds are two
// block-uniform loads (L2-resident). emb loads are nontemporal (read-once,
// 201 MB — don't evict the word tensor kernel B re-reads).
// ---------------------------------------------------------------------------
__global__ __launch_bounds__(D4) void word_agg_kernel(
    const floatx4* __restrict__ emb, const int* __restrict__ wb, floatx4* __restrict__ word)
{
    const int g = blockIdx.x;
    const int b = blockIdx.y;
    const int lo = wb[b * WB_STRIDE + g];
    const int hi = wb[b * WB_STRIDE + g + 1];
    const int d = threadIdx.x;

    floatx4 acc = (floatx4)(0.f);
    for (int s = lo; s < hi; ++s) {
#pragma unroll
        for (int l = 0; l < LL; ++l) {
            floatx4 v = __builtin_nontemporal_load(
                &emb[((size_t)((b * LL + l) * SS + s)) * D4 + d]);
            acc += v;
        }
    }
    word[((size_t)(b * SS + g)) * D4 + d] = acc;
}

// ---------------------------------------------------------------------------
// Kernel B: seg_embeddings[b,t,:] = sum_{g in [sb[t],sb[t+1])} word[b,g,:]
// ---------------------------------------------------------------------------
__global__ __launch_bounds__(D4) void seg_agg_kernel(
    const floatx4* __restrict__ word, const int* __restrict__ sb, floatx4* __restrict__ seg)
{
    const int t = blockIdx.x;
    const int b = blockIdx.y;
    const int lo = sb[b * SB_STRIDE + t];
    const int hi = sb[b * SB_STRIDE + t + 1];
    const int d = threadIdx.x;

    floatx4 acc = (floatx4)(0.f);
    for (int g = lo; g < hi; ++g) {
        acc += word[((size_t)(b * SS + g)) * D4 + d];
    }
    seg[((size_t)(b * GG + t)) * D4 + d] = acc;
}

// ---------------------------------------------------------------------------
// Kernel C: sent_embeddings[b,:] = (1/512) * sum_t seg[b,t,:]  (segment_sum over
// all 512 padded word slots partitions them across segments), plus
// seg_mask[b,j] = (j >= sg[b,511]+1) as 0/1 floats (sorted -> last elem is max).
// ---------------------------------------------------------------------------
__global__ __launch_bounds__(D4) void sent_mask_kernel(
    const floatx4* __restrict__ seg, const int* __restrict__ sg,
    floatx4* __restrict__ sent, float* __restrict__ mask)
{
    const int b = blockIdx.x;
    const int d = threadIdx.x;

    floatx4 acc = (floatx4)(0.f);
#pragma unroll
    for (int t = 0; t < GG; ++t) {
        acc += seg[((size_t)(b * GG + t)) * D4 + d];
    }
    acc *= (1.0f / (float)SS);
    sent[(size_t)b * D4 + d] = acc;

    if (d < GG) {
        const int seg_num = sg[b * SS + (SS - 1)] + 1;
        mask[b * GG + d] = (d >= seg_num) ? 1.0f : 0.0f;
    }
}

extern "C" void kernel_launch(void* const* d_in, const int* in_sizes, int n_in,
                              void* d_out, int out_size, void* d_ws, size_t ws_size,
                              hipStream_t stream) {
    const float* emb = (const float*)d_in[0];           // [32,4,512,768] fp32
    const int*   tg  = (const int*)d_in[1];             // [32,512]
    const int*   sg  = (const int*)d_in[2];             // [32,512]

    float* out  = (float*)d_out;
    float* word = out;                                   // [32,512,768]
    float* sent = word + (size_t)BB * SS * DD;           // [32,768]
    float* seg  = sent + (size_t)BB * DD;                // [32,24,768]
    float* mask = seg  + (size_t)BB * GG * DD;           // [32,24]

    int* wb = (int*)d_ws;                                // [32][513]
    int* sb = wb + BB * WB_STRIDE;                       // [32][25]

    bounds_kernel<<<BB, SS, 0, stream>>>(tg, sg, wb, sb);
    word_agg_kernel<<<dim3(SS, BB), D4, 0, stream>>>((const floatx4*)emb, wb, (floatx4*)word);
    seg_agg_kernel<<<dim3(GG, BB), D4, 0, stream>>>((const floatx4*)word, sb, (floatx4*)seg);
    sent_mask_kernel<<<BB, D4, 0, stream>>>((const floatx4*)seg, sg, (floatx4*)sent, mask);
}